// Round 16
// baseline (268.554 us; speedup 1.0000x reference)
//
#include <hip/hip_runtime.h>
#include <hip/hip_bf16.h>

// ---------------------------------------------------------------------------
// CausalSelfAttention: out = softmax_causal((X Wqkv + b) QK^T/sqrt(d)) V, proj
// B=2 S=2048 E=2048 H=16 HD=128.  bf16 MFMA everywhere, fp32 softmax/accum.
// ---------------------------------------------------------------------------

typedef unsigned short u16;
typedef unsigned int   u32;
typedef __attribute__((ext_vector_type(4)))  float f32x4;
typedef __attribute__((ext_vector_type(16))) float f32x16;
typedef __attribute__((ext_vector_type(4)))  unsigned int u32x4;
typedef __attribute__((ext_vector_type(4)))  unsigned short u16x4;
typedef __attribute__((ext_vector_type(8)))  unsigned short u16x8;
typedef __attribute__((ext_vector_type(8)))  short bf16x8;   // 8 bf16 = 4 VGPR

#define E_    2048
#define H_    16
#define HD_   128
#define S_    2048
#define B_    2
#define M_    (B_ * S_)       // 4096 rows of X
#define N1_   (3 * E_)        // 6144
static constexpr float SCALE = 0.08838834764831845f;  // 1/sqrt(128)
static constexpr float C2LOG = 0.12752224f;           // SCALE * log2(e)

#define AS1 __attribute__((address_space(1)))
#define AS3 __attribute__((address_space(3)))

__device__ __forceinline__ u16 f2bf(float f) {
  union { float f; u32 u; } x; x.f = f;
  u32 r = x.u + 0x7fffu + ((x.u >> 16) & 1u);   // RNE
  return (u16)(r >> 16);
}
__device__ __forceinline__ float bfhi2f(u32 u) {   // high 16 bits as bf16
  union { u32 u; float f; } x; x.u = u & 0xffff0000u; return x.f;
}
__device__ __forceinline__ float bflo2f(u32 u) {   // low 16 bits as bf16
  union { u32 u; float f; } x; x.u = u << 16; return x.f;
}
// {lo:bf16(a), hi:bf16(b)} -- library RNE pack (lowers to v_cvt_pk_bf16_f32)
__device__ __forceinline__ u32 pk2(float a, float b) {
  union { __hip_bfloat162 h; u32 u; } c;
  c.h = __float22bfloat162_rn(make_float2(a, b));
  return c.u;
}

// ---------------------------------------------------------------- cvt fp32->bf16
__global__ __launch_bounds__(256) void cvt_bf16(const float* __restrict__ x,
                                                u16* __restrict__ y, int n) {
  int i = (blockIdx.x * 256 + threadIdx.x) * 8;
  if (i >= n) return;
  f32x4 a = *(const f32x4*)(x + i);
  f32x4 b = *(const f32x4*)(x + i + 4);
  u16x4 u0 = { f2bf(a[0]), f2bf(a[1]), f2bf(a[2]), f2bf(a[3]) };
  u16x4 u1 = { f2bf(b[0]), f2bf(b[1]), f2bf(b[2]), f2bf(b[3]) };
  *(u16x4*)(y + i)     = u0;
  *(u16x4*)(y + i + 4) = u1;
}

// --------------------------------------------- transpose+convert W[r][c] -> Wt[c][r] bf16
__global__ __launch_bounds__(256) void transpose_cvt_f32(const float* __restrict__ W,
                                                         u16* __restrict__ Wt,
                                                         int rows, int cols) {
  __shared__ __align__(16) u16 tile[64][68];  // +4 pad
  const int ct = blockIdx.x, rt = blockIdx.y;
  const int tid = threadIdx.x;
  const int seg = tid & 15, r0 = tid >> 4;
  for (int p = 0; p < 4; ++p) {
    int r = r0 + p * 16;
    f32x4 f = *(const f32x4*)&W[(size_t)(rt * 64 + r) * cols + ct * 64 + seg * 4];
    u16x4 u = { f2bf(f[0]), f2bf(f[1]), f2bf(f[2]), f2bf(f[3]) };
    *(u16x4*)&tile[r][seg * 4] = u;
  }
  __syncthreads();
  for (int p = 0; p < 4; ++p) {
    int oc = r0 + p * 16;
    u16x4 u = { tile[seg * 4 + 0][oc], tile[seg * 4 + 1][oc],
                tile[seg * 4 + 2][oc], tile[seg * 4 + 3][oc] };
    *(u16x4*)&Wt[(size_t)(ct * 64 + oc) * rows + rt * 64 + seg * 4] = u;
  }
}

// --------------------------------------------- 128x128 bf16 GEMM, Bt is [N][K]
// (r13-verified: BK=64, dbuf 64KB -> 2 blocks/CU, counted vmcnt(8), XOR swizzle,
// setprio around MFMA.  Output projection ONLY: grid must be 16x32.)
// XCD-locality remap (T1): lin = x8 + 8*t2 + 16*mm  (bijective) -> each XCD
// owns bn pair {2*x8, 2*x8+1} => its 1MB of B-panels stays in its private L2.
template<int OUT_F32>
__global__ __launch_bounds__(256) void gemm_bt(const u16* __restrict__ A,
                                               const u16* __restrict__ Bt,
                                               const float* __restrict__ bias,
                                               void* __restrict__ Cp,
                                               int M, int N, int K) {
  const int lin = (int)blockIdx.x + 16 * (int)blockIdx.y;   // grid 16x32 = 512
  const int bn = 2 * (lin & 7) + ((lin >> 3) & 1);
  const int bm = lin >> 4;
  const int tid = threadIdx.x;
  const int wid = tid >> 6, l = tid & 63;
  const int l15 = l & 15, l4 = l >> 4;
  const int wr = wid >> 1, wc = wid & 1;

  __shared__ __align__(16) u16 SH[32768];
  u16* Asp = SH;
  u16* Bsp = SH + 16384;

  f32x4 acc[4][4] = {};

  const int srow  = l >> 3;
  const int sslot = (l & 7) ^ srow;
  const u16* gA = A  + (size_t)(bm * 128 + srow) * K + sslot * 8;
  const u16* gB = Bt + (size_t)(bn * 128 + srow) * K + sslot * 8;

  auto stage = [&](int buf, int kt) {
#pragma unroll
    for (int i = 0; i < 4; ++i) {
      const int rb = i * 32 + wid * 8;
      __builtin_amdgcn_global_load_lds(
          (AS1 const void*)(gA + (size_t)rb * K + kt),
          (AS3 void*)(Asp + buf * 8192 + rb * 64), 16, 0, 0);
      __builtin_amdgcn_global_load_lds(
          (AS1 const void*)(gB + (size_t)rb * K + kt),
          (AS3 void*)(Bsp + buf * 8192 + rb * 64), 16, 0, 0);
    }
  };

  stage(0, 0);
  const int nk = K >> 6;
  for (int n = 0; n < nk; ++n) {
    const int buf = n & 1;
    if (n + 1 < nk) {
      stage(buf ^ 1, (n + 1) << 6);
      asm volatile("s_waitcnt vmcnt(8)" ::: "memory");
    } else {
      asm volatile("s_waitcnt vmcnt(0)" ::: "memory");
    }
    __syncthreads();

#pragma unroll
    for (int ks = 0; ks < 2; ++ks) {
      bf16x8 af[4], bfr[4];
      const int ph = ((ks * 4 + l4) ^ (l15 & 7)) * 8;
#pragma unroll
      for (int i = 0; i < 4; ++i) {
        af[i]  = *(const bf16x8*)&Asp[buf * 8192 + (wr * 64 + i * 16 + l15) * 64 + ph];
        bfr[i] = *(const bf16x8*)&Bsp[buf * 8192 + (wc * 64 + i * 16 + l15) * 64 + ph];
      }
      __builtin_amdgcn_s_setprio(1);
#pragma unroll
      for (int mi = 0; mi < 4; ++mi)
#pragma unroll
        for (int ni = 0; ni < 4; ++ni)
          acc[mi][ni] = __builtin_amdgcn_mfma_f32_16x16x32_bf16(af[mi], bfr[ni],
                                                                acc[mi][ni], 0, 0, 0);
      __builtin_amdgcn_s_setprio(0);
    }
    __syncthreads();
  }

  for (int ni = 0; ni < 4; ++ni) {
    int col = bn * 128 + wc * 64 + ni * 16 + l15;
    float bs = bias[col];
    for (int mi = 0; mi < 4; ++mi) {
      int row = bm * 128 + wr * 64 + mi * 16 + l4 * 4;
      for (int j = 0; j < 4; ++j) {
        float v = acc[mi][ni][j] + bs;
        if (OUT_F32) ((float*)Cp)[(size_t)(row + j) * N + col] = v;
        else         ((u16*)Cp)[(size_t)(row + j) * N + col] = f2bf(v);
      }
    }
  }
}

// --------------------------------------------- 128x256 bf16 GEMM, Bt is [N][K]
// (r14-verified: BM=128 BN=256 BK=64, 8 waves 2Mx4N, 96KB dbuf, 4-phase K-tile,
// boundary vmcnt(2), XOR swizzle, setprio.  QKV projection ONLY: grid 24x32 =
// 768 blocks = 3 exact rounds.  VSPLIT=1: V columns written transposed.)
// XCD-locality remap (T1): lin = x8 + 8*t3 + 24*mm (bijective for grid 24x32)
// -> each XCD owns bn triple {3*x8..3*x8+2} => its 3MB of B-panels fit its L2.
template<int OUT_F32, int VSPLIT>
__global__ __launch_bounds__(512) void gemm_bt2(const u16* __restrict__ A,
                                                const u16* __restrict__ Bt,
                                                const float* __restrict__ bias,
                                                void* __restrict__ Cp,
                                                u16* __restrict__ vt,
                                                int M, int N, int K) {
  const int lin = (int)blockIdx.x + 24 * (int)blockIdx.y;   // grid 24x32 = 768
  const int bn = 3 * (lin & 7) + ((lin >> 3) % 3);
  const int bm = lin / 24;
  const int tid = threadIdx.x;
  const int wid = tid >> 6, l = tid & 63;
  const int l15 = l & 15, l4 = l >> 4;
  const int wr = wid >> 2, wc = wid & 3;   // 2M x 4N wave grid

  __shared__ __align__(16) u16 SH[49152];
  u16* Asb = SH;
  u16* Bsb = SH + 16384;

  f32x4 acc[4][4] = {};

  const int srow  = tid >> 3;              // 0..63
  const int sslot = (tid & 7) ^ (srow & 7);
  const u16* gA = A  + (size_t)(bm * 128 + srow) * K + sslot * 8;
  const u16* gB = Bt + (size_t)(bn * 256 + srow) * K + sslot * 8;

  auto issueA = [&](int buf, int kt, int i) {   // i in {0,1}
    __builtin_amdgcn_global_load_lds(
        (AS1 const void*)(gA + (size_t)(i * 64) * K + kt),
        (AS3 void*)(Asb + buf * 8192 + (i * 64 + wid * 8) * 64), 16, 0, 0);
  };
  auto issueB = [&](int buf, int kt, int i) {   // i in {0..3}
    __builtin_amdgcn_global_load_lds(
        (AS1 const void*)(gB + (size_t)(i * 64) * K + kt),
        (AS3 void*)(Bsb + buf * 16384 + (i * 64 + wid * 8) * 64), 16, 0, 0);
  };

  issueA(0, 0, 0); issueA(0, 0, 1);
#pragma unroll
  for (int i = 0; i < 4; ++i) issueB(0, 0, i);

  const int nk = K >> 6;
  for (int n = 0; n < nk; ++n) {
    const int buf = n & 1;
    const int kt1 = (n + 1) << 6;
    const bool more = (n + 1 < nk);

    if (more) {
      issueA(buf ^ 1, kt1, 0); issueA(buf ^ 1, kt1, 1);
      asm volatile("s_waitcnt vmcnt(2)" ::: "memory");
    } else {
      asm volatile("s_waitcnt vmcnt(0)" ::: "memory");
    }
    __builtin_amdgcn_s_barrier();

    const u16* Ab = Asb + buf * 8192  + (size_t)(wr * 64) * 64;
    const u16* Bb = Bsb + buf * 16384 + (size_t)(wc * 64) * 64;
    const int ph0 = (l4 ^ (l15 & 7)) * 8;
    const int ph1 = ((4 + l4) ^ (l15 & 7)) * 8;

    bf16x8 af[2], bfr[4];
    // ---- phase 0: mh=0, kh=0 ----
#pragma unroll
    for (int i = 0; i < 2; ++i)
      af[i] = *(const bf16x8*)(Ab + (size_t)(i * 16 + l15) * 64 + ph0);
#pragma unroll
    for (int i = 0; i < 4; ++i)
      bfr[i] = *(const bf16x8*)(Bb + (size_t)(i * 16 + l15) * 64 + ph0);
    if (more) { issueB(buf ^ 1, kt1, 0); issueB(buf ^ 1, kt1, 1); }
    __builtin_amdgcn_s_setprio(1);
#pragma unroll
    for (int mi = 0; mi < 2; ++mi)
#pragma unroll
      for (int ni = 0; ni < 4; ++ni)
        acc[mi][ni] = __builtin_amdgcn_mfma_f32_16x16x32_bf16(af[mi], bfr[ni],
                                                              acc[mi][ni], 0, 0, 0);
    __builtin_amdgcn_s_setprio(0);
    __builtin_amdgcn_s_barrier();

    // ---- phase 1: mh=1, kh=0 ----
#pragma unroll
    for (int i = 0; i < 2; ++i)
      af[i] = *(const bf16x8*)(Ab + (size_t)(32 + i * 16 + l15) * 64 + ph0);
    if (more) { issueB(buf ^ 1, kt1, 2); issueB(buf ^ 1, kt1, 3); }
    __builtin_amdgcn_s_setprio(1);
#pragma unroll
    for (int mi = 0; mi < 2; ++mi)
#pragma unroll
      for (int ni = 0; ni < 4; ++ni)
        acc[2 + mi][ni] = __builtin_amdgcn_mfma_f32_16x16x32_bf16(af[mi], bfr[ni],
                                                                  acc[2 + mi][ni], 0, 0, 0);
    __builtin_amdgcn_s_setprio(0);
    __builtin_amdgcn_s_barrier();

    // ---- phase 2: mh=0, kh=1 ----
#pragma unroll
    for (int i = 0; i < 2; ++i)
      af[i] = *(const bf16x8*)(Ab + (size_t)(i * 16 + l15) * 64 + ph1);
#pragma unroll
    for (int i = 0; i < 4; ++i)
      bfr[i] = *(const bf16x8*)(Bb + (size_t)(i * 16 + l15) * 64 + ph1);
    __builtin_amdgcn_s_setprio(1);
#pragma unroll
    for (int mi = 0; mi < 2; ++mi)
#pragma unroll
      for (int ni = 0; ni < 4; ++ni)
        acc[mi][ni] = __builtin_amdgcn_mfma_f32_16x16x32_bf16(af[mi], bfr[ni],
                                                              acc[mi][ni], 0, 0, 0);
    __builtin_amdgcn_s_setprio(0);
    __builtin_amdgcn_s_barrier();

    // ---- phase 3: mh=1, kh=1 ----
#pragma unroll
    for (int i = 0; i < 2; ++i)
      af[i] = *(const bf16x8*)(Ab + (size_t)(32 + i * 16 + l15) * 64 + ph1);
    __builtin_amdgcn_s_setprio(1);
#pragma unroll
    for (int mi = 0; mi < 2; ++mi)
#pragma unroll
      for (int ni = 0; ni < 4; ++ni)
        acc[2 + mi][ni] = __builtin_amdgcn_mfma_f32_16x16x32_bf16(af[mi], bfr[ni],
                                                                  acc[2 + mi][ni], 0, 0, 0);
    __builtin_amdgcn_s_setprio(0);
    __builtin_amdgcn_s_barrier();
  }

  if (VSPLIT && bn * 256 >= 2 * E_) {
    // ---- V block: transpose through LDS, coalesced vt writes ----
    u16* T = SH;   // [256][136]
#pragma unroll
    for (int ni = 0; ni < 4; ++ni) {
      const int d = wc * 64 + ni * 16 + l15;               // tile-local d (0..255)
      const float bs = bias[bn * 256 + d];
#pragma unroll
      for (int mi = 0; mi < 4; ++mi) {
        const int s = wr * 64 + mi * 16 + l4 * 4;          // tile-local s (0..127)
        u16x4 u = { f2bf(acc[mi][ni][0] + bs), f2bf(acc[mi][ni][1] + bs),
                    f2bf(acc[mi][ni][2] + bs), f2bf(acc[mi][ni][3] + bs) };
        *(u16x4*)&T[d * 136 + s] = u;
      }
    }
    __syncthreads();
    const int d = tid >> 1, sh = (tid & 1) * 64;
    const int b = (bm * 128) >> 11, sbase = (bm * 128) & 2047;
    const int h0 = (bn * 256 - 2 * E_) >> 7;
    u16* vrow = vt + (((size_t)(b * H_ + h0 + (d >> 7))) * HD_ + (d & 127)) * S_
              + sbase + sh;
#pragma unroll
    for (int i = 0; i < 8; ++i)
      *(u16x8*)&vrow[i * 8] = *(const u16x8*)&T[d * 136 + sh + i * 8];
  } else {
    for (int ni = 0; ni < 4; ++ni) {
      int col = bn * 256 + wc * 64 + ni * 16 + l15;
      float bs = bias[col];
      for (int mi = 0; mi < 4; ++mi) {
        int row = bm * 128 + wr * 64 + mi * 16 + l4 * 4;
        for (int j = 0; j < 4; ++j) {
          float v = acc[mi][ni][j] + bs;
          if (OUT_F32) ((float*)Cp)[(size_t)(row + j) * N + col] = v;
          else         ((u16*)Cp)[(size_t)(row + j) * N + col] = f2bf(v);
        }
      }
    }
  }
}

// --------------------------------------------- flash attention v3b, causal
// grid: (16, 32) = 512 blocks. Load-balanced remap: linear id i -> bh = i&31,
// qt = (i>>5)<8 ? i>>5 : 23-(i>>5).  CU residents (i, i+256) then hold
// (qt, 15-qt) -> every CU gets 17 work units, and both share the same bh.
__global__ __launch_bounds__(256) void attn3(const u16* __restrict__ qkv,
                                             const u16* __restrict__ vt,
                                             u16* __restrict__ outp) {
  const int i_lin = (int)blockIdx.x + 16 * (int)blockIdx.y;
  const int bh = i_lin & 31;
  const int h8 = i_lin >> 5;                 // 0..15
  const int qt = (h8 < 8) ? h8 : 23 - h8;    // pair (qt, 15-qt) per CU
  const int b = bh >> 4, h = bh & 15;
  const int tid = threadIdx.x;
  const int w = tid >> 6, l = tid & 63;
  const int l31 = l & 31, hi = l >> 5, l15 = l & 15, l4 = l >> 4;

  __shared__ __align__(16) u16 Ks[128 * 128];   // [token r][dim], 256B rows, swizzled
  __shared__ __align__(16) u16 Vs[128 * 128];   // [dim d][128 tok pair], swizzled

  const int q_glob = qt * 128 + w * 32 + l31;
  const int qmin_w = qt * 128 + w * 32;
  const int qmax_w = qmin_w + 31;

  // ---- Q fragments, pre-scaled by SCALE*log2(e) (B-operand: [q][k] contig-k) ----
  bf16x8 qf[8];
  {
    const u16* qrow = qkv + (size_t)(b * S_ + q_glob) * N1_ + h * HD_;
#pragma unroll
    for (int kd = 0; kd < 8; ++kd) {
      u32x4 raw = *(const u32x4*)(qrow + kd * 16 + hi * 8);
      u32x4 o;
#pragma unroll
      for (int j = 0; j < 4; ++j)
        o[j] = pk2(bflo2f(raw[j]) * C2LOG, bfhi2f(raw[j]) * C2LOG);
      union { u32x4 u; bf16x8 b; } cv; cv.u = o; qf[kd] = cv.b;
    }
  }

  // per-lane swizzled 16B-slot offsets (elem units); all reads have row&15 == l15
  int slotKe[8];
#pragma unroll
  for (int kd = 0; kd < 8; ++kd) slotKe[kd] = ((2 * kd + hi) ^ l15) * 8;

  f32x16 o0 = {}, o1 = {}, o2 = {}, o3 = {};   // O^T; row=d, col=q(l31)
  float m_run = -1e30f, lsum = 0.f;

  const int pairs = qt + 1;
  for (int t = 0; t < pairs; ++t) {
    __syncthreads();   // everyone done reading previous pair
    // ---- stage K (32KB) + V (32KB): 8 wave-issues of 1KB each ----
#pragma unroll
    for (int i = 0; i < 8; ++i) {
      const int rowbase = i * 16 + w * 4;
      const int r = rowbase + l4;
      const int e = (l15 ^ (r & 15)) * 8;
      __builtin_amdgcn_global_load_lds(
          (AS1 const void*)
              (qkv + (size_t)(b * S_ + t * 128 + r) * N1_ + E_ + h * HD_ + e),
          (AS3 void*)(Ks + rowbase * 128), 16, 0, 0);
      __builtin_amdgcn_global_load_lds(
          (AS1 const void*)
              (vt + (size_t)(bh * HD_ + r) * S_ + t * 128 + e),
          (AS3 void*)(Vs + rowbase * 128), 16, 0, 0);
    }
    asm volatile("s_waitcnt vmcnt(0)");
    __syncthreads();

#pragma unroll
    for (int p = 0; p < 2; ++p) {
      const int kbase = t * 128 + p * 64;
      if (kbase > qmax_w) continue;          // wave-uniform skip

      // ---- QK^T (swapped): sc = K * Q^T, [64 k][32 q] per wave ----
      f32x16 sc0 = {}, sc1 = {};
#pragma unroll
      for (int kd = 0; kd < 8; ++kd) {
        bf16x8 ka0 = *(const bf16x8*)(Ks + (size_t)(p * 64 + l31) * 128 + slotKe[kd]);
        bf16x8 ka1 = *(const bf16x8*)(Ks + (size_t)(p * 64 + 32 + l31) * 128 + slotKe[kd]);
        sc0 = __builtin_amdgcn_mfma_f32_32x32x16_bf16(ka0, qf[kd], sc0, 0, 0, 0);
        sc1 = __builtin_amdgcn_mfma_f32_32x32x16_bf16(ka1, qf[kd], sc1, 0, 0, 0);
      }

      // ---- causal mask (diagonal chunks only); k = kbase+32kf+8(r>>2)+4hi+(r&3)
      if (kbase + 63 > qmin_w) {
#pragma unroll
        for (int r = 0; r < 16; ++r) {
          int k0 = kbase + 8 * (r >> 2) + 4 * hi + (r & 3);
          if (k0 > q_glob)      sc0[r] = -1e30f;
          if (k0 + 32 > q_glob) sc1[r] = -1e30f;
        }
      }

      // ---- lane-local online softmax (scores already in log2 domain) ----
      float tm = -1e30f;
#pragma unroll
      for (int r = 0; r < 16; ++r) tm = fmaxf(tm, fmaxf(sc0[r], sc1[r]));
      tm = fmaxf(tm, __shfl_xor(tm, 32));    // combine hi/lo halves (same q)
      if (tm > m_run + 8.0f) {               // rescale (rare after first chunk)
        float alpha = exp2f(m_run - tm);
        m_run = tm;
        lsum *= alpha;
#pragma unroll
        for (int r = 0; r < 16; ++r) {
          o0[r] *= alpha; o1[r] *= alpha; o2[r] *= alpha; o3[r] *= alpha;
        }
      }
      float s0 = 0.f, s1 = 0.f;
#pragma unroll
      for (int r = 0; r < 16; ++r) {
        float p0 = exp2f(sc0[r] - m_run); sc0[r] = p0; s0 += p0;
        float p1 = exp2f(sc1[r] - m_run); sc1[r] = p1; s1 += p1;
      }
      lsum += s0 + s1;

      // ---- pack P into PV B-fragments: shfl_xor(32) exchange, no asm ----
      bf16x8 pf[4];
#pragma unroll
      for (int kd = 0; kd < 4; ++kd) {
        const f32x16& scf = (kd < 2) ? sc0 : sc1;
        const int rb = (kd & 1) * 8;
        u32 xa = pk2(scf[rb + 0], scf[rb + 1]);
        u32 ya = pk2(scf[rb + 2], scf[rb + 3]);
        u32 xb = pk2(scf[rb + 4], scf[rb + 5]);
        u32 yb = pk2(scf[rb + 6], scf[rb + 7]);
        u32 sxa = __shfl_xor(xa, 32), sya = __shfl_xor(ya, 32);
        u32 sxb = __shfl_xor(xb, 32), syb = __shfl_xor(yb, 32);
        u32x4 fw;
        fw[0] = hi ? sxb : xa;   fw[1] = hi ? syb : ya;   // j=0..3 (hiS=0 source)
        fw[2] = hi ? xb  : sxa;  fw[3] = hi ? yb  : sya;  // j=4..7 (hiS=1 source)
        union { u32x4 u; bf16x8 b; } cv; cv.u = fw; pf[kd] = cv.b;
      }

      // ---- PV: O^T += V^T * P  (A = V^T rows [d][tok], B = P [tok][q]) ----
#pragma unroll
      for (int kd = 0; kd < 4; ++kd) {
        const int vofs = slotKe[kd] ^ (p * 64);
        bf16x8 va0 = *(const bf16x8*)(Vs + (size_t)(0  + l31) * 128 + vofs);
        bf16x8 va1 = *(const bf16x8*)(Vs + (size_t)(32 + l31) * 128 + vofs);
        bf16x8 va2 = *(const bf16x8*)(Vs + (size_t)(64 + l31) * 128 + vofs);
        bf16x8 va3 = *(const bf16x8*)(Vs + (size_t)(96 + l31) * 128 + vofs);
        o0 = __builtin_amdgcn_mfma_f32_32x32x16_bf16(va0, pf[kd], o0, 0, 0, 0);
        o1 = __builtin_amdgcn_mfma_f32_32x32x16_bf16(va1, pf[kd], o1, 0, 0, 0);
        o2 = __builtin_amdgcn_mfma_f32_32x32x16_bf16(va2, pf[kd], o2, 0, 0, 0);
        o3 = __builtin_amdgcn_mfma_f32_32x32x16_bf16(va3, pf[kd], o3, 0, 0, 0);
      }
    }
  }

  // ---- epilogue: combine half-sums, normalize, store bf16 ----
  lsum += __shfl_xor(lsum, 32);
  const float inv = 1.0f / lsum;
  u16* orow = outp + (size_t)(b * S_ + q_glob) * E_ + h * HD_;
#pragma unroll
  for (int df = 0; df < 4; ++df) {
    const f32x16& oo = (df == 0) ? o0 : (df == 1) ? o1 : (df == 2) ? o2 : o3;
#pragma unroll
    for (int g = 0; g < 4; ++g) {
      int d = 32 * df + 8 * g + 4 * hi;
      u16x4 u = { f2bf(oo[g * 4 + 0] * inv), f2bf(oo[g * 4 + 1] * inv),
                  f2bf(oo[g * 4 + 2] * inv), f2bf(oo[g * 4 + 3] * inv) };
      *(u16x4*)(orow + d) = u;
    }
  }
}

// ---------------------------------------------------------------------------
extern "C" void kernel_launch(void* const* d_in, const int* in_sizes, int n_in,
                              void* d_out, int out_size, void* d_ws, size_t ws_size,
                              hipStream_t stream) {
  const float* inX  = (const float*)d_in[0];
  const float* Wqkv = (const float*)d_in[1];
  const float* bqkv = (const float*)d_in[2];
  const float* Wout = (const float*)d_in[3];
  const float* bout = (const float*)d_in[4];

  char* ws = (char*)d_ws;
  // layout: [Xb 16M | Wqt 24M | Wot 8M | QKV 48M | Vt 16M]  (112 MB total)
  u16* Xb   = (u16*)(ws);
  u16* Wqt  = (u16*)(ws + (16u << 20));
  u16* Wot  = (u16*)(ws + (40u << 20));
  u16* QKV  = (u16*)(ws + (48u << 20));
  u16* Vt   = (u16*)(ws + (96u << 20));
  u16* Attn = Xb;

  cvt_bf16<<<(M_ * E_) / (256 * 8), 256, 0, stream>>>(inX, Xb, M_ * E_);
  transpose_cvt_f32<<<dim3(N1_ / 64, E_ / 64), 256, 0, stream>>>(Wqkv, Wqt, E_, N1_);
  transpose_cvt_f32<<<dim3(E_ / 64, E_ / 64), 256, 0, stream>>>(Wout, Wot, E_, E_);
  gemm_bt2<0, 1><<<dim3(N1_ / 256, M_ / 128), 512, 0, stream>>>(Xb, Wqt, bqkv,
                                                                (void*)QKV, Vt,
                                                                M_, N1_, E_);
  attn3<<<dim3(16, 32), 256, 0, stream>>>(QKV, Vt, Attn);
  gemm_bt<1><<<dim3(E_ / 128, M_ / 128), 256, 0, stream>>>(Attn, Wot, bout,
                                                           d_out, M_, E_, E_);
}

// Round 17
// 262.958 us; speedup vs baseline: 1.0213x; 1.0213x over previous
//
#include <hip/hip_runtime.h>
#include <hip/hip_bf16.h>

// ---------------------------------------------------------------------------
// CausalSelfAttention: out = softmax_causal((X Wqkv + b) QK^T/sqrt(d)) V, proj
// B=2 S=2048 E=2048 H=16 HD=128.  bf16 MFMA everywhere, fp32 softmax/accum.
// ---------------------------------------------------------------------------

typedef unsigned short u16;
typedef unsigned int   u32;
typedef __attribute__((ext_vector_type(4)))  float f32x4;
typedef __attribute__((ext_vector_type(16))) float f32x16;
typedef __attribute__((ext_vector_type(4)))  unsigned int u32x4;
typedef __attribute__((ext_vector_type(4)))  unsigned short u16x4;
typedef __attribute__((ext_vector_type(8)))  unsigned short u16x8;
typedef __attribute__((ext_vector_type(8)))  short bf16x8;   // 8 bf16 = 4 VGPR

#define E_    2048
#define H_    16
#define HD_   128
#define S_    2048
#define B_    2
#define M_    (B_ * S_)       // 4096 rows of X
#define N1_   (3 * E_)        // 6144
static constexpr float SCALE = 0.08838834764831845f;  // 1/sqrt(128)
static constexpr float C2LOG = 0.12752224f;           // SCALE * log2(e)

#define AS1 __attribute__((address_space(1)))
#define AS3 __attribute__((address_space(3)))

__device__ __forceinline__ u16 f2bf(float f) {
  union { float f; u32 u; } x; x.f = f;
  u32 r = x.u + 0x7fffu + ((x.u >> 16) & 1u);   // RNE
  return (u16)(r >> 16);
}
__device__ __forceinline__ float bfhi2f(u32 u) {   // high 16 bits as bf16
  union { u32 u; float f; } x; x.u = u & 0xffff0000u; return x.f;
}
__device__ __forceinline__ float bflo2f(u32 u) {   // low 16 bits as bf16
  union { u32 u; float f; } x; x.u = u << 16; return x.f;
}
// {lo:bf16(a), hi:bf16(b)} -- library RNE pack (lowers to v_cvt_pk_bf16_f32)
__device__ __forceinline__ u32 pk2(float a, float b) {
  union { __hip_bfloat162 h; u32 u; } c;
  c.h = __float22bfloat162_rn(make_float2(a, b));
  return c.u;
}

// ---------------------------------------------------------------- cvt fp32->bf16
__global__ __launch_bounds__(256) void cvt_bf16(const float* __restrict__ x,
                                                u16* __restrict__ y, int n) {
  int i = (blockIdx.x * 256 + threadIdx.x) * 8;
  if (i >= n) return;
  f32x4 a = *(const f32x4*)(x + i);
  f32x4 b = *(const f32x4*)(x + i + 4);
  u16x4 u0 = { f2bf(a[0]), f2bf(a[1]), f2bf(a[2]), f2bf(a[3]) };
  u16x4 u1 = { f2bf(b[0]), f2bf(b[1]), f2bf(b[2]), f2bf(b[3]) };
  *(u16x4*)(y + i)     = u0;
  *(u16x4*)(y + i + 4) = u1;
}

// --------------------------------------------- transpose+convert W[r][c] -> Wt[c][r] bf16
__global__ __launch_bounds__(256) void transpose_cvt_f32(const float* __restrict__ W,
                                                         u16* __restrict__ Wt,
                                                         int rows, int cols) {
  __shared__ __align__(16) u16 tile[64][68];  // +4 pad
  const int ct = blockIdx.x, rt = blockIdx.y;
  const int tid = threadIdx.x;
  const int seg = tid & 15, r0 = tid >> 4;
  for (int p = 0; p < 4; ++p) {
    int r = r0 + p * 16;
    f32x4 f = *(const f32x4*)&W[(size_t)(rt * 64 + r) * cols + ct * 64 + seg * 4];
    u16x4 u = { f2bf(f[0]), f2bf(f[1]), f2bf(f[2]), f2bf(f[3]) };
    *(u16x4*)&tile[r][seg * 4] = u;
  }
  __syncthreads();
  for (int p = 0; p < 4; ++p) {
    int oc = r0 + p * 16;
    u16x4 u = { tile[seg * 4 + 0][oc], tile[seg * 4 + 1][oc],
                tile[seg * 4 + 2][oc], tile[seg * 4 + 3][oc] };
    *(u16x4*)&Wt[(size_t)(ct * 64 + oc) * rows + rt * 64 + seg * 4] = u;
  }
}

// --------------------------------------------- 128x128 bf16 GEMM, Bt is [N][K]
// (r13-verified: BK=64, dbuf 64KB -> 2 blocks/CU, counted vmcnt(8), XOR swizzle,
// setprio around MFMA.  Used for the output projection.)
template<int OUT_F32>
__global__ __launch_bounds__(256) void gemm_bt(const u16* __restrict__ A,
                                               const u16* __restrict__ Bt,
                                               const float* __restrict__ bias,
                                               void* __restrict__ Cp,
                                               int M, int N, int K) {
  const int bn = blockIdx.x, bm = blockIdx.y;
  const int tid = threadIdx.x;
  const int wid = tid >> 6, l = tid & 63;
  const int l15 = l & 15, l4 = l >> 4;
  const int wr = wid >> 1, wc = wid & 1;

  __shared__ __align__(16) u16 SH[32768];
  u16* Asp = SH;
  u16* Bsp = SH + 16384;

  f32x4 acc[4][4] = {};

  const int srow  = l >> 3;
  const int sslot = (l & 7) ^ srow;
  const u16* gA = A  + (size_t)(bm * 128 + srow) * K + sslot * 8;
  const u16* gB = Bt + (size_t)(bn * 128 + srow) * K + sslot * 8;

  auto stage = [&](int buf, int kt) {
#pragma unroll
    for (int i = 0; i < 4; ++i) {
      const int rb = i * 32 + wid * 8;
      __builtin_amdgcn_global_load_lds(
          (AS1 const void*)(gA + (size_t)rb * K + kt),
          (AS3 void*)(Asp + buf * 8192 + rb * 64), 16, 0, 0);
      __builtin_amdgcn_global_load_lds(
          (AS1 const void*)(gB + (size_t)rb * K + kt),
          (AS3 void*)(Bsp + buf * 8192 + rb * 64), 16, 0, 0);
    }
  };

  stage(0, 0);
  const int nk = K >> 6;
  for (int n = 0; n < nk; ++n) {
    const int buf = n & 1;
    if (n + 1 < nk) {
      stage(buf ^ 1, (n + 1) << 6);
      asm volatile("s_waitcnt vmcnt(8)" ::: "memory");
    } else {
      asm volatile("s_waitcnt vmcnt(0)" ::: "memory");
    }
    __syncthreads();

#pragma unroll
    for (int ks = 0; ks < 2; ++ks) {
      bf16x8 af[4], bfr[4];
      const int ph = ((ks * 4 + l4) ^ (l15 & 7)) * 8;
#pragma unroll
      for (int i = 0; i < 4; ++i) {
        af[i]  = *(const bf16x8*)&Asp[buf * 8192 + (wr * 64 + i * 16 + l15) * 64 + ph];
        bfr[i] = *(const bf16x8*)&Bsp[buf * 8192 + (wc * 64 + i * 16 + l15) * 64 + ph];
      }
      __builtin_amdgcn_s_setprio(1);
#pragma unroll
      for (int mi = 0; mi < 4; ++mi)
#pragma unroll
        for (int ni = 0; ni < 4; ++ni)
          acc[mi][ni] = __builtin_amdgcn_mfma_f32_16x16x32_bf16(af[mi], bfr[ni],
                                                                acc[mi][ni], 0, 0, 0);
      __builtin_amdgcn_s_setprio(0);
    }
    __syncthreads();
  }

  for (int ni = 0; ni < 4; ++ni) {
    int col = bn * 128 + wc * 64 + ni * 16 + l15;
    float bs = bias[col];
    for (int mi = 0; mi < 4; ++mi) {
      int row = bm * 128 + wr * 64 + mi * 16 + l4 * 4;
      for (int j = 0; j < 4; ++j) {
        float v = acc[mi][ni][j] + bs;
        if (OUT_F32) ((float*)Cp)[(size_t)(row + j) * N + col] = v;
        else         ((u16*)Cp)[(size_t)(row + j) * N + col] = f2bf(v);
      }
    }
  }
}

// --------------------------------------------- 128x256 bf16 GEMM, Bt is [N][K]
// (r14-verified: BM=128 BN=256 BK=64, 8 waves 2Mx4N, 96KB dbuf, 4-phase K-tile,
// boundary vmcnt(2), XOR swizzle, setprio.  GEMM1: 24x32 = 768 blocks = 3 exact
// rounds.  VSPLIT=1: V columns written transposed to vt[b,h,d,s] via LDS.)
template<int OUT_F32, int VSPLIT>
__global__ __launch_bounds__(512) void gemm_bt2(const u16* __restrict__ A,
                                                const u16* __restrict__ Bt,
                                                const float* __restrict__ bias,
                                                void* __restrict__ Cp,
                                                u16* __restrict__ vt,
                                                int M, int N, int K) {
  const int bn = blockIdx.x, bm = blockIdx.y;
  const int tid = threadIdx.x;
  const int wid = tid >> 6, l = tid & 63;
  const int l15 = l & 15, l4 = l >> 4;
  const int wr = wid >> 2, wc = wid & 3;   // 2M x 4N wave grid

  __shared__ __align__(16) u16 SH[49152];
  u16* Asb = SH;
  u16* Bsb = SH + 16384;

  f32x4 acc[4][4] = {};

  const int srow  = tid >> 3;              // 0..63
  const int sslot = (tid & 7) ^ (srow & 7);
  const u16* gA = A  + (size_t)(bm * 128 + srow) * K + sslot * 8;
  const u16* gB = Bt + (size_t)(bn * 256 + srow) * K + sslot * 8;

  auto issueA = [&](int buf, int kt, int i) {   // i in {0,1}
    __builtin_amdgcn_global_load_lds(
        (AS1 const void*)(gA + (size_t)(i * 64) * K + kt),
        (AS3 void*)(Asb + buf * 8192 + (i * 64 + wid * 8) * 64), 16, 0, 0);
  };
  auto issueB = [&](int buf, int kt, int i) {   // i in {0..3}
    __builtin_amdgcn_global_load_lds(
        (AS1 const void*)(gB + (size_t)(i * 64) * K + kt),
        (AS3 void*)(Bsb + buf * 16384 + (i * 64 + wid * 8) * 64), 16, 0, 0);
  };

  issueA(0, 0, 0); issueA(0, 0, 1);
#pragma unroll
  for (int i = 0; i < 4; ++i) issueB(0, 0, i);

  const int nk = K >> 6;
  for (int n = 0; n < nk; ++n) {
    const int buf = n & 1;
    const int kt1 = (n + 1) << 6;
    const bool more = (n + 1 < nk);

    if (more) {
      issueA(buf ^ 1, kt1, 0); issueA(buf ^ 1, kt1, 1);
      asm volatile("s_waitcnt vmcnt(2)" ::: "memory");
    } else {
      asm volatile("s_waitcnt vmcnt(0)" ::: "memory");
    }
    __builtin_amdgcn_s_barrier();

    const u16* Ab = Asb + buf * 8192  + (size_t)(wr * 64) * 64;
    const u16* Bb = Bsb + buf * 16384 + (size_t)(wc * 64) * 64;
    const int ph0 = (l4 ^ (l15 & 7)) * 8;
    const int ph1 = ((4 + l4) ^ (l15 & 7)) * 8;

    bf16x8 af[2], bfr[4];
    // ---- phase 0: mh=0, kh=0 ----
#pragma unroll
    for (int i = 0; i < 2; ++i)
      af[i] = *(const bf16x8*)(Ab + (size_t)(i * 16 + l15) * 64 + ph0);
#pragma unroll
    for (int i = 0; i < 4; ++i)
      bfr[i] = *(const bf16x8*)(Bb + (size_t)(i * 16 + l15) * 64 + ph0);
    if (more) { issueB(buf ^ 1, kt1, 0); issueB(buf ^ 1, kt1, 1); }
    __builtin_amdgcn_s_setprio(1);
#pragma unroll
    for (int mi = 0; mi < 2; ++mi)
#pragma unroll
      for (int ni = 0; ni < 4; ++ni)
        acc[mi][ni] = __builtin_amdgcn_mfma_f32_16x16x32_bf16(af[mi], bfr[ni],
                                                              acc[mi][ni], 0, 0, 0);
    __builtin_amdgcn_s_setprio(0);
    __builtin_amdgcn_s_barrier();

    // ---- phase 1: mh=1, kh=0 ----
#pragma unroll
    for (int i = 0; i < 2; ++i)
      af[i] = *(const bf16x8*)(Ab + (size_t)(32 + i * 16 + l15) * 64 + ph0);
    if (more) { issueB(buf ^ 1, kt1, 2); issueB(buf ^ 1, kt1, 3); }
    __builtin_amdgcn_s_setprio(1);
#pragma unroll
    for (int mi = 0; mi < 2; ++mi)
#pragma unroll
      for (int ni = 0; ni < 4; ++ni)
        acc[2 + mi][ni] = __builtin_amdgcn_mfma_f32_16x16x32_bf16(af[mi], bfr[ni],
                                                                  acc[2 + mi][ni], 0, 0, 0);
    __builtin_amdgcn_s_setprio(0);
    __builtin_amdgcn_s_barrier();

    // ---- phase 2: mh=0, kh=1 ----
#pragma unroll
    for (int i = 0; i < 2; ++i)
      af[i] = *(const bf16x8*)(Ab + (size_t)(i * 16 + l15) * 64 + ph1);
#pragma unroll
    for (int i = 0; i < 4; ++i)
      bfr[i] = *(const bf16x8*)(Bb + (size_t)(i * 16 + l15) * 64 + ph1);
    __builtin_amdgcn_s_setprio(1);
#pragma unroll
    for (int mi = 0; mi < 2; ++mi)
#pragma unroll
      for (int ni = 0; ni < 4; ++ni)
        acc[mi][ni] = __builtin_amdgcn_mfma_f32_16x16x32_bf16(af[mi], bfr[ni],
                                                              acc[mi][ni], 0, 0, 0);
    __builtin_amdgcn_s_setprio(0);
    __builtin_amdgcn_s_barrier();

    // ---- phase 3: mh=1, kh=1 ----
#pragma unroll
    for (int i = 0; i < 2; ++i)
      af[i] = *(const bf16x8*)(Ab + (size_t)(32 + i * 16 + l15) * 64 + ph1);
    __builtin_amdgcn_s_setprio(1);
#pragma unroll
    for (int mi = 0; mi < 2; ++mi)
#pragma unroll
      for (int ni = 0; ni < 4; ++ni)
        acc[2 + mi][ni] = __builtin_amdgcn_mfma_f32_16x16x32_bf16(af[mi], bfr[ni],
                                                                  acc[2 + mi][ni], 0, 0, 0);
    __builtin_amdgcn_s_setprio(0);
    __builtin_amdgcn_s_barrier();
  }

  if (VSPLIT && bn * 256 >= 2 * E_) {
    // ---- V block: transpose through LDS, coalesced vt writes ----
    u16* T = SH;   // [256][136]
#pragma unroll
    for (int ni = 0; ni < 4; ++ni) {
      const int d = wc * 64 + ni * 16 + l15;               // tile-local d (0..255)
      const float bs = bias[bn * 256 + d];
#pragma unroll
      for (int mi = 0; mi < 4; ++mi) {
        const int s = wr * 64 + mi * 16 + l4 * 4;          // tile-local s (0..127)
        u16x4 u = { f2bf(acc[mi][ni][0] + bs), f2bf(acc[mi][ni][1] + bs),
                    f2bf(acc[mi][ni][2] + bs), f2bf(acc[mi][ni][3] + bs) };
        *(u16x4*)&T[d * 136 + s] = u;
      }
    }
    __syncthreads();
    const int d = tid >> 1, sh = (tid & 1) * 64;
    const int b = (bm * 128) >> 11, sbase = (bm * 128) & 2047;
    const int h0 = (bn * 256 - 2 * E_) >> 7;
    u16* vrow = vt + (((size_t)(b * H_ + h0 + (d >> 7))) * HD_ + (d & 127)) * S_
              + sbase + sh;
#pragma unroll
    for (int i = 0; i < 8; ++i)
      *(u16x8*)&vrow[i * 8] = *(const u16x8*)&T[d * 136 + sh + i * 8];
  } else {
    for (int ni = 0; ni < 4; ++ni) {
      int col = bn * 256 + wc * 64 + ni * 16 + l15;
      float bs = bias[col];
      for (int mi = 0; mi < 4; ++mi) {
        int row = bm * 128 + wr * 64 + mi * 16 + l4 * 4;
        for (int j = 0; j < 4; ++j) {
          float v = acc[mi][ni][j] + bs;
          if (OUT_F32) ((float*)Cp)[(size_t)(row + j) * N + col] = v;
          else         ((u16*)Cp)[(size_t)(row + j) * N + col] = f2bf(v);
        }
      }
    }
  }
}

// --------------------------------------------- flash attention v3b, causal
// grid: (16, 32) = 512 blocks. Load-balanced remap: linear id i -> bh = i&31,
// qt = (i>>5)<8 ? i>>5 : 23-(i>>5).  CU residents (i, i+256) then hold
// (qt, 15-qt) -> every CU gets 17 work units, and both share the same bh.
__global__ __launch_bounds__(256) void attn3(const u16* __restrict__ qkv,
                                             const u16* __restrict__ vt,
                                             u16* __restrict__ outp) {
  const int i_lin = (int)blockIdx.x + 16 * (int)blockIdx.y;
  const int bh = i_lin & 31;
  const int h8 = i_lin >> 5;                 // 0..15
  const int qt = (h8 < 8) ? h8 : 23 - h8;    // pair (qt, 15-qt) per CU
  const int b = bh >> 4, h = bh & 15;
  const int tid = threadIdx.x;
  const int w = tid >> 6, l = tid & 63;
  const int l31 = l & 31, hi = l >> 5, l15 = l & 15, l4 = l >> 4;

  __shared__ __align__(16) u16 Ks[128 * 128];   // [token r][dim], 256B rows, swizzled
  __shared__ __align__(16) u16 Vs[128 * 128];   // [dim d][128 tok pair], swizzled

  const int q_glob = qt * 128 + w * 32 + l31;
  const int qmin_w = qt * 128 + w * 32;
  const int qmax_w = qmin_w + 31;

  // ---- Q fragments, pre-scaled by SCALE*log2(e) (B-operand: [q][k] contig-k) ----
  bf16x8 qf[8];
  {
    const u16* qrow = qkv + (size_t)(b * S_ + q_glob) * N1_ + h * HD_;
#pragma unroll
    for (int kd = 0; kd < 8; ++kd) {
      u32x4 raw = *(const u32x4*)(qrow + kd * 16 + hi * 8);
      u32x4 o;
#pragma unroll
      for (int j = 0; j < 4; ++j)
        o[j] = pk2(bflo2f(raw[j]) * C2LOG, bfhi2f(raw[j]) * C2LOG);
      union { u32x4 u; bf16x8 b; } cv; cv.u = o; qf[kd] = cv.b;
    }
  }

  // per-lane swizzled 16B-slot offsets (elem units); all reads have row&15 == l15
  int slotKe[8];
#pragma unroll
  for (int kd = 0; kd < 8; ++kd) slotKe[kd] = ((2 * kd + hi) ^ l15) * 8;

  f32x16 o0 = {}, o1 = {}, o2 = {}, o3 = {};   // O^T; row=d, col=q(l31)
  float m_run = -1e30f, lsum = 0.f;

  const int pairs = qt + 1;
  for (int t = 0; t < pairs; ++t) {
    __syncthreads();   // everyone done reading previous pair
    // ---- stage K (32KB) + V (32KB): 8 wave-issues of 1KB each ----
#pragma unroll
    for (int i = 0; i < 8; ++i) {
      const int rowbase = i * 16 + w * 4;
      const int r = rowbase + l4;
      const int e = (l15 ^ (r & 15)) * 8;
      __builtin_amdgcn_global_load_lds(
          (AS1 const void*)
              (qkv + (size_t)(b * S_ + t * 128 + r) * N1_ + E_ + h * HD_ + e),
          (AS3 void*)(Ks + rowbase * 128), 16, 0, 0);
      __builtin_amdgcn_global_load_lds(
          (AS1 const void*)
              (vt + (size_t)(bh * HD_ + r) * S_ + t * 128 + e),
          (AS3 void*)(Vs + rowbase * 128), 16, 0, 0);
    }
    asm volatile("s_waitcnt vmcnt(0)");
    __syncthreads();

#pragma unroll
    for (int p = 0; p < 2; ++p) {
      const int kbase = t * 128 + p * 64;
      if (kbase > qmax_w) continue;          // wave-uniform skip

      // ---- QK^T (swapped): sc = K * Q^T, [64 k][32 q] per wave ----
      f32x16 sc0 = {}, sc1 = {};
#pragma unroll
      for (int kd = 0; kd < 8; ++kd) {
        bf16x8 ka0 = *(const bf16x8*)(Ks + (size_t)(p * 64 + l31) * 128 + slotKe[kd]);
        bf16x8 ka1 = *(const bf16x8*)(Ks + (size_t)(p * 64 + 32 + l31) * 128 + slotKe[kd]);
        sc0 = __builtin_amdgcn_mfma_f32_32x32x16_bf16(ka0, qf[kd], sc0, 0, 0, 0);
        sc1 = __builtin_amdgcn_mfma_f32_32x32x16_bf16(ka1, qf[kd], sc1, 0, 0, 0);
      }

      // ---- causal mask (diagonal chunks only); k = kbase+32kf+8(r>>2)+4hi+(r&3)
      if (kbase + 63 > qmin_w) {
#pragma unroll
        for (int r = 0; r < 16; ++r) {
          int k0 = kbase + 8 * (r >> 2) + 4 * hi + (r & 3);
          if (k0 > q_glob)      sc0[r] = -1e30f;
          if (k0 + 32 > q_glob) sc1[r] = -1e30f;
        }
      }

      // ---- lane-local online softmax (scores already in log2 domain) ----
      float tm = -1e30f;
#pragma unroll
      for (int r = 0; r < 16; ++r) tm = fmaxf(tm, fmaxf(sc0[r], sc1[r]));
      tm = fmaxf(tm, __shfl_xor(tm, 32));    // combine hi/lo halves (same q)
      if (tm > m_run + 8.0f) {               // rescale (rare after first chunk)
        float alpha = exp2f(m_run - tm);
        m_run = tm;
        lsum *= alpha;
#pragma unroll
        for (int r = 0; r < 16; ++r) {
          o0[r] *= alpha; o1[r] *= alpha; o2[r] *= alpha; o3[r] *= alpha;
        }
      }
      float s0 = 0.f, s1 = 0.f;
#pragma unroll
      for (int r = 0; r < 16; ++r) {
        float p0 = exp2f(sc0[r] - m_run); sc0[r] = p0; s0 += p0;
        float p1 = exp2f(sc1[r] - m_run); sc1[r] = p1; s1 += p1;
      }
      lsum += s0 + s1;

      // ---- pack P into PV B-fragments: shfl_xor(32) exchange, no asm ----
      bf16x8 pf[4];
#pragma unroll
      for (int kd = 0; kd < 4; ++kd) {
        const f32x16& scf = (kd < 2) ? sc0 : sc1;
        const int rb = (kd & 1) * 8;
        u32 xa = pk2(scf[rb + 0], scf[rb + 1]);
        u32 ya = pk2(scf[rb + 2], scf[rb + 3]);
        u32 xb = pk2(scf[rb + 4], scf[rb + 5]);
        u32 yb = pk2(scf[rb + 6], scf[rb + 7]);
        u32 sxa = __shfl_xor(xa, 32), sya = __shfl_xor(ya, 32);
        u32 sxb = __shfl_xor(xb, 32), syb = __shfl_xor(yb, 32);
        u32x4 fw;
        fw[0] = hi ? sxb : xa;   fw[1] = hi ? syb : ya;   // j=0..3 (hiS=0 source)
        fw[2] = hi ? xb  : sxa;  fw[3] = hi ? yb  : sya;  // j=4..7 (hiS=1 source)
        union { u32x4 u; bf16x8 b; } cv; cv.u = fw; pf[kd] = cv.b;
      }

      // ---- PV: O^T += V^T * P  (A = V^T rows [d][tok], B = P [tok][q]) ----
#pragma unroll
      for (int kd = 0; kd < 4; ++kd) {
        const int vofs = slotKe[kd] ^ (p * 64);
        bf16x8 va0 = *(const bf16x8*)(Vs + (size_t)(0  + l31) * 128 + vofs);
        bf16x8 va1 = *(const bf16x8*)(Vs + (size_t)(32 + l31) * 128 + vofs);
        bf16x8 va2 = *(const bf16x8*)(Vs + (size_t)(64 + l31) * 128 + vofs);
        bf16x8 va3 = *(const bf16x8*)(Vs + (size_t)(96 + l31) * 128 + vofs);
        o0 = __builtin_amdgcn_mfma_f32_32x32x16_bf16(va0, pf[kd], o0, 0, 0, 0);
        o1 = __builtin_amdgcn_mfma_f32_32x32x16_bf16(va1, pf[kd], o1, 0, 0, 0);
        o2 = __builtin_amdgcn_mfma_f32_32x32x16_bf16(va2, pf[kd], o2, 0, 0, 0);
        o3 = __builtin_amdgcn_mfma_f32_32x32x16_bf16(va3, pf[kd], o3, 0, 0, 0);
      }
    }
  }

  // ---- epilogue: combine half-sums, normalize, store bf16 ----
  lsum += __shfl_xor(lsum, 32);
  const float inv = 1.0f / lsum;
  u16* orow = outp + (size_t)(b * S_ + q_glob) * E_ + h * HD_;
#pragma unroll
  for (int df = 0; df < 4; ++df) {
    const f32x16& oo = (df == 0) ? o0 : (df == 1) ? o1 : (df == 2) ? o2 : o3;
#pragma unroll
    for (int g = 0; g < 4; ++g) {
      int d = 32 * df + 8 * g + 4 * hi;
      u16x4 u = { f2bf(oo[g * 4 + 0] * inv), f2bf(oo[g * 4 + 1] * inv),
                  f2bf(oo[g * 4 + 2] * inv), f2bf(oo[g * 4 + 3] * inv) };
      *(u16x4*)(orow + d) = u;
    }
  }
}

// ---------------------------------------------------------------------------
extern "C" void kernel_launch(void* const* d_in, const int* in_sizes, int n_in,
                              void* d_out, int out_size, void* d_ws, size_t ws_size,
                              hipStream_t stream) {
  const float* inX  = (const float*)d_in[0];
  const float* Wqkv = (const float*)d_in[1];
  const float* bqkv = (const float*)d_in[2];
  const float* Wout = (const float*)d_in[3];
  const float* bout = (const float*)d_in[4];

  char* ws = (char*)d_ws;
  // layout: [Xb 16M | Wqt 24M | Wot 8M | QKV 48M | Vt 16M]  (112 MB total)
  u16* Xb   = (u16*)(ws);
  u16* Wqt  = (u16*)(ws + (16u << 20));
  u16* Wot  = (u16*)(ws + (40u << 20));
  u16* QKV  = (u16*)(ws + (48u << 20));
  u16* Vt   = (u16*)(ws + (96u << 20));
  u16* Attn = Xb;

  cvt_bf16<<<(M_ * E_) / (256 * 8), 256, 0, stream>>>(inX, Xb, M_ * E_);
  transpose_cvt_f32<<<dim3(N1_ / 64, E_ / 64), 256, 0, stream>>>(Wqkv, Wqt, E_, N1_);
  transpose_cvt_f32<<<dim3(E_ / 64, E_ / 64), 256, 0, stream>>>(Wout, Wot, E_, E_);
  gemm_bt2<0, 1><<<dim3(N1_ / 256, M_ / 128), 512, 0, stream>>>(Xb, Wqt, bqkv,
                                                                (void*)QKV, Vt,
                                                                M_, N1_, E_);
  attn3<<<dim3(16, 32), 256, 0, stream>>>(QKV, Vt, Attn);
  gemm_bt<1><<<dim3(E_ / 128, M_ / 128), 256, 0, stream>>>(Attn, Wot, bout,
                                                           d_out, M_, E_, E_);
}